// Round 1
// baseline (606.663 us; speedup 1.0000x reference)
//
#include <hip/hip_runtime.h>
#include <hip/hip_bf16.h>
#include <stdint.h>

#define LVLS 16
#define TSZ  524288          // hash table size per level (2^19)
#define TMASK 0x7FFFFu
#define NPTS 524288
#define P1 2654435761u
#define P2 805459861u
#define P3 3674653429u

// floor(16 * 1.5^l), hardcoded
__constant__ float RES_TAB[16] = {
    16.f, 24.f, 36.f, 54.f, 81.f, 121.f, 182.f, 273.f,
    410.f, 615.f, 922.f, 1383.f, 2075.f, 3113.f, 4670.f, 7006.f};

using f16x8 = __attribute__((ext_vector_type(8))) _Float16;
using f32x4 = __attribute__((ext_vector_type(4))) float;

union PackF16 { uint32_t u; _Float16 h[2]; };

constexpr int PS = 72;    // LDS row pitch (64 cols + 8 pad)

struct WPtrs { const float* p[11]; };

// ---------------------------------------------------------------------------
// Kernel B: XCD-pinned table build + weight swizzle (merged). Unchanged.
// ---------------------------------------------------------------------------
__global__ void k_build(const float* __restrict__ ts, const float* __restrict__ td,
                        const float* __restrict__ tptr, uint2* __restrict__ Tc,
                        WPtrs wp, _Float16* __restrict__ wdst) {
    int B = blockIdx.x;
    int tid = threadIdx.x;
    if (B < 40960) {
        int c = B & 7, j = B >> 3;
        int l, i;
        if (j < 1024) {
            l = c >> 1;
            i = (c & 1) * 262144 + j * 256 + tid;
        } else if (j < 3072) {
            l = 12 + (c >> 1);
            i = (j - 1024) * 256 + tid;
        } else {
            l = 4 + c;
            i = (j - 3072) * 256 + tid;
        }
        int id = l * TSZ + i;
        float2 sv = ((const float2*)ts)[id];
        float res = RES_TAB[l];
        float tv  = tptr[0];
        float pt  = tv * res;
        float fpt = floorf(pt);
        float ft  = pt - fpt;
        uint32_t ut = (uint32_t)(int)fpt;
        uint32_t h0 = (ut * P3) & TMASK;
        uint32_t h1 = ((ut + 1u) * P3) & TMASK;
        const float2* tdl = (const float2*)td + (size_t)l * TSZ;
        float2 a = tdl[i ^ h0];
        float2 b = tdl[i ^ h1];
        PackF16 o0, o1;
        o0.h[0] = (_Float16)sv.x; o0.h[1] = (_Float16)sv.y;
        o1.h[0] = (_Float16)((1.f - ft) * a.x + ft * b.x);
        o1.h[1] = (_Float16)((1.f - ft) * a.y + ft * b.y);
        Tc[id] = make_uint2(o0.u, o1.u);
    } else {
        int id = (B - 40960) * 256 + tid;
        if (id >= 69632) return;
        const int OFF[16] = {0,2048,6144,10240,14336,18432,20480,24576,28672,
                             32768,36864,45056,49152,57344,65536,69632};
        const int KK[15]  = {32,64,64,64,64,32,64,64,64,64,128,64,64,128,64};
        const int NN[15]  = {64,64,64,64,64,64,64,64,64,64,64,64,128,64,64};
        const int PSEL[15]= {0,1,1,1,2,3,4,4,4,5,6,7,8,9,10};
        const int POFF[15]= {0,0,4096,8192,0,0,0,4096,8192,0,0,0,0,0,0};
        int m = 0;
        while (id >= OFF[m+1]) m++;
        int local = id - OFF[m];
        int jj   = local & 7;
        int lane = (local >> 3) & 63;
        int blk  = local >> 9;
        int KC   = KK[m] >> 5;
        int ct   = blk / KC;
        int kc   = blk - ct * KC;
        int k    = kc*32 + ((lane>>4)<<3) + jj;
        int n    = ct*16 + (lane & 15);
        const float* src = wp.p[PSEL[m]] + POFF[m];
        wdst[id] = (_Float16)src[k * NN[m] + n];
    }
}

// ---------------------------------------------------------------------------
// Kernel E: hash-grid encode, XCD-sharded (unchanged schedule), but the
// inner loop now batches Q=4 points: compute 32 gather addresses, issue all
// 32 global_load_dwordx2 back-to-back, THEN accumulate. Raises per-wave
// outstanding loads 8 -> 32 (counted vmcnt lets point-0 accumulation start
// while points 1..3 are still in flight). VGPR ~110, launch_bounds(256,4)
// -> 4 waves/SIMD x 32 loads = 128 in flight/SIMD vs ~34 before.
// ---------------------------------------------------------------------------
template<int Q>
__device__ __forceinline__ void enc_batch(const float* __restrict__ x,
                                          const uint2* __restrict__ tcl, float res,
                                          uint32_t* __restrict__ es,
                                          uint32_t* __restrict__ ed,
                                          int p0, int stride) {
    uint2 v[Q][8];
    float wx[Q], wy[Q], wz[Q];
#pragma unroll
    for (int q = 0; q < Q; q++) {
        int p = p0 + q * stride;
        float px = x[p*3+0]*res, py = x[p*3+1]*res, pz = x[p*3+2]*res;
        float fx = floorf(px), fy = floorf(py), fz = floorf(pz);
        wx[q] = px-fx; wy[q] = py-fy; wz[q] = pz-fz;
        uint32_t ux = (uint32_t)(int)fx, uy = (uint32_t)(int)fy, uz = (uint32_t)(int)fz;
        uint32_t hx[2] = {ux, ux + 1u};
        uint32_t hy[2] = {uy * P1, (uy + 1u) * P1};
        uint32_t hz[2] = {uz * P2, (uz + 1u) * P2};
#pragma unroll
        for (int c = 0; c < 8; c++) {
            uint32_t idx = (hx[c&1] ^ hy[(c>>1)&1] ^ hz[c>>2]) & TMASK;
            v[q][c] = tcl[idx];
        }
    }
#pragma unroll
    for (int q = 0; q < Q; q++) {
        float wxa[2] = {1.f-wx[q], wx[q]};
        float wya[2] = {1.f-wy[q], wy[q]};
        float wza[2] = {1.f-wz[q], wz[q]};
        float sA0 = 0.f, sA1 = 0.f, sD0 = 0.f, sD1 = 0.f;
#pragma unroll
        for (int c = 0; c < 8; c++) {
            float w = wxa[c&1] * wya[(c>>1)&1] * wza[c>>2];
            PackF16 s, d; s.u = v[q][c].x; d.u = v[q][c].y;
            sA0 += w * (float)s.h[0]; sA1 += w * (float)s.h[1];
            sD0 += w * (float)d.h[0]; sD1 += w * (float)d.h[1];
        }
        int p = p0 + q * stride;
        PackF16 o;
        o.h[0] = (_Float16)sA0; o.h[1] = (_Float16)sA1; es[p] = o.u;
        o.h[0] = (_Float16)sD0; o.h[1] = (_Float16)sD1; ed[p] = o.u;
    }
}

__launch_bounds__(256, 4)
__global__ void k_encode(const float* __restrict__ x,
                         const uint2* __restrict__ Tc,
                         uint32_t* __restrict__ EncS, uint32_t* __restrict__ EncD) {
    int tid = threadIdx.x;
    int c   = blockIdx.x & 7;
    int gt  = (blockIdx.x >> 3) * 256 + tid;   // 0..65535 within class
    // pass 0: exclusive hard level (hot from k_build) — 8 points, 2 batches
    {
        int l = 4 + c;
        const uint2* tcl = Tc + (size_t)l * TSZ;
        uint32_t* es = EncS + (size_t)l * NPTS;
        uint32_t* ed = EncD + (size_t)l * NPTS;
        float res = RES_TAB[l];
        enc_batch<4>(x, tcl, res, es, ed, gt,             65536);
        enc_batch<4>(x, tcl, res, es, ed, gt + 4 * 65536, 65536);
    }
    // pass 1: shared hard level, half point-set — 4 points, 1 batch
    {
        int l = 12 + (c >> 1);
        const uint2* tcl = Tc + (size_t)l * TSZ;
        uint32_t* es = EncS + (size_t)l * NPTS;
        uint32_t* ed = EncD + (size_t)l * NPTS;
        float res = RES_TAB[l];
        int pb = (c & 1) * 262144 + gt;
        enc_batch<4>(x, tcl, res, es, ed, pb, 65536);
    }
    // pass 2: coarse level, half point-set — 4 points, 1 batch
    {
        int l = c >> 1;
        const uint2* tcl = Tc + (size_t)l * TSZ;
        uint32_t* es = EncS + (size_t)l * NPTS;
        uint32_t* ed = EncD + (size_t)l * NPTS;
        float res = RES_TAB[l];
        int pb = (c & 1) * 262144 + gt;
        enc_batch<4>(x, tcl, res, es, ed, pb, 65536);
    }
}

// ---------------------------------------------------------------------------
// Kernel M: barrier-free MLP (r5/r6-verified, unchanged).
// ---------------------------------------------------------------------------
__device__ __forceinline__ void wait_lds() {
    asm volatile("s_waitcnt lgkmcnt(0)" ::: "memory");
}

template<int KC, bool RELU>
__device__ __forceinline__ void mm2(const f16x8 a[2][4], const f16x8* __restrict__ B,
                                    _Float16* dst, int m, int quad, int lane) {
#pragma unroll
    for (int ct = 0; ct < 4; ct++) {
        f32x4 acc0 = {0.f,0.f,0.f,0.f}, acc1 = {0.f,0.f,0.f,0.f};
#pragma unroll
        for (int kc = 0; kc < KC; kc++) {
            f16x8 b = B[(ct*KC+kc)*64 + lane];
            acc0 = __builtin_amdgcn_mfma_f32_16x16x32_f16(a[0][kc], b, acc0, 0, 0, 0);
            acc1 = __builtin_amdgcn_mfma_f32_16x16x32_f16(a[1][kc], b, acc1, 0, 0, 0);
        }
#pragma unroll
        for (int i = 0; i < 4; i++) {
            float v0 = acc0[i], v1 = acc1[i];
            if (RELU) { v0 = fmaxf(v0, 0.f); v1 = fmaxf(v1, 0.f); }
            dst[(0*16 + quad*4+i)*PS + ct*16 + m] = (_Float16)v0;
            dst[(1*16 + quad*4+i)*PS + ct*16 + m] = (_Float16)v1;
        }
    }
}

template<int KC>
__device__ __forceinline__ void mm2_keep(const f16x8 a[2][4], const f16x8* __restrict__ B,
                                         _Float16* dst, PackF16 P[2][8],
                                         int m, int quad, int lane) {
#pragma unroll
    for (int ct = 0; ct < 4; ct++) {
        f32x4 acc0 = {0.f,0.f,0.f,0.f}, acc1 = {0.f,0.f,0.f,0.f};
#pragma unroll
        for (int kc = 0; kc < KC; kc++) {
            f16x8 b = B[(ct*KC+kc)*64 + lane];
            acc0 = __builtin_amdgcn_mfma_f32_16x16x32_f16(a[0][kc], b, acc0, 0, 0, 0);
            acc1 = __builtin_amdgcn_mfma_f32_16x16x32_f16(a[1][kc], b, acc1, 0, 0, 0);
        }
#pragma unroll
        for (int ih = 0; ih < 2; ih++) {
            PackF16 p0, p1;
            p0.h[0] = (_Float16)acc0[ih*2+0]; p0.h[1] = (_Float16)acc0[ih*2+1];
            p1.h[0] = (_Float16)acc1[ih*2+0]; p1.h[1] = (_Float16)acc1[ih*2+1];
            P[0][ct*2+ih] = p0; P[1][ct*2+ih] = p1;
            dst[(0*16 + quad*4+ih*2+0)*PS + ct*16 + m] = p0.h[0];
            dst[(0*16 + quad*4+ih*2+1)*PS + ct*16 + m] = p0.h[1];
            dst[(1*16 + quad*4+ih*2+0)*PS + ct*16 + m] = p1.h[0];
            dst[(1*16 + quad*4+ih*2+1)*PS + ct*16 + m] = p1.h[1];
        }
    }
}

template<int KC>
__device__ __forceinline__ void read_a(const _Float16* buf, f16x8 a[2][4], int m, int quad) {
#pragma unroll
    for (int rt = 0; rt < 2; rt++)
#pragma unroll
        for (int kc = 0; kc < KC; kc++)
            a[rt][kc] = *(const f16x8*)(buf + (rt*16 + m)*PS + kc*32 + quad*8);
}

__device__ __forceinline__ void read_a128(const _Float16* Fs, const _Float16* Fd,
                                          f16x8 a[2][4], int m, int quad) {
#pragma unroll
    for (int rt = 0; rt < 2; rt++) {
#pragma unroll
        for (int kc = 0; kc < 2; kc++) {
            a[rt][kc]   = *(const f16x8*)(Fs + (rt*16 + m)*PS + kc*32 + quad*8);
            a[rt][kc+2] = *(const f16x8*)(Fd + (rt*16 + m)*PS + kc*32 + quad*8);
        }
    }
}

__device__ __forceinline__ void load_enc(const uint32_t* __restrict__ Enc,
                                         int pbase, int m, int quad, f16x8 a[2][4]) {
#pragma unroll
    for (int rt = 0; rt < 2; rt++) {
        union { uint32_t u[4]; f16x8 v; } cv;
        int p = pbase + rt*16 + m;
#pragma unroll
        for (int j = 0; j < 4; j++)
            cv.u[j] = Enc[(size_t)(quad*4 + j) * NPTS + p];
        a[rt][0] = cv.v;
    }
}

__launch_bounds__(256, 4)
__global__ void k_mlp(const uint32_t* __restrict__ EncS, const uint32_t* __restrict__ EncD,
                      const _Float16* __restrict__ Wfrag, const float* __restrict__ alphap,
                      const float* __restrict__ w2out, float* __restrict__ out) {
    __shared__ _Float16 FsB[4][32*PS];
    __shared__ _Float16 FdB[4][32*PS];
    int tid  = threadIdx.x;
    int wave = tid >> 6, lane = tid & 63;
    int m = lane & 15, quad = lane >> 4;
    int pbase = blockIdx.x * 128 + wave * 32;
    _Float16* Fs = FsB[wave];
    _Float16* Fd = FdB[wave];
    const f16x8* W8 = (const f16x8*)Wfrag;
    float alpha = alphap[0];

    f16x8 a[2][4];
    PackF16 sP[2][8], dP[2][8];

    // ---- static encoder chain, in-place in Fs ----
    load_enc(EncS, pbase, m, quad, a);
    mm2<1, true>(a, W8 + 0,    Fs, m, quad, lane); wait_lds();
    read_a<2>(Fs, a, m, quad);
    mm2<2, true>(a, W8 + 256,  Fs, m, quad, lane); wait_lds();
    read_a<2>(Fs, a, m, quad);
    mm2<2, true>(a, W8 + 768,  Fs, m, quad, lane); wait_lds();
    read_a<2>(Fs, a, m, quad);
    mm2<2, true>(a, W8 + 1280, Fs, m, quad, lane); wait_lds();
    read_a<2>(Fs, a, m, quad);
    mm2_keep<2>(a, W8 + 1792, Fs, sP, m, quad, lane);
    // ---- dynamic encoder chain, in-place in Fd ----
    load_enc(EncD, pbase, m, quad, a);
    mm2<1, true>(a, W8 + 2304, Fd, m, quad, lane); wait_lds();
    read_a<2>(Fd, a, m, quad);
    mm2<2, true>(a, W8 + 2560, Fd, m, quad, lane); wait_lds();
    read_a<2>(Fd, a, m, quad);
    mm2<2, true>(a, W8 + 3072, Fd, m, quad, lane); wait_lds();
    read_a<2>(Fd, a, m, quad);
    mm2<2, true>(a, W8 + 3584, Fd, m, quad, lane); wait_lds();
    read_a<2>(Fd, a, m, quad);
    mm2_keep<2>(a, W8 + 4096, Fd, dP, m, quad, lane); wait_lds();
    // ---- mlp1: 128->64 relu (reads Fs|Fd, writes Fs), 64->64 relu ----
    read_a128(Fs, Fd, a, m, quad);
    mm2<4, true>(a, W8 + 4608, Fs, m, quad, lane); wait_lds();
    read_a<2>(Fs, a, m, quad);
    mm2<2, true>(a, W8 + 5632, Fs, m, quad, lane); wait_lds();
    read_a<2>(Fs, a, m, quad);
    // ---- out1 (64->128) fused with skip blend -> Fs (cols 0..63) | Fd ----
#pragma unroll
    for (int ct = 0; ct < 8; ct++) {
        f32x4 acc0 = {0.f,0.f,0.f,0.f}, acc1 = {0.f,0.f,0.f,0.f};
#pragma unroll
        for (int kc = 0; kc < 2; kc++) {
            f16x8 b = W8[6144 + (ct*2+kc)*64 + lane];
            acc0 = __builtin_amdgcn_mfma_f32_16x16x32_f16(a[0][kc], b, acc0, 0, 0, 0);
            acc1 = __builtin_amdgcn_mfma_f32_16x16x32_f16(a[1][kc], b, acc1, 0, 0, 0);
        }
        _Float16* tgt = (ct < 4) ? Fs : Fd;
        int col = (ct & 3) * 16 + m;
#pragma unroll
        for (int i = 0; i < 4; i++) {
            float f0 = (ct < 4) ? (float)sP[0][ct*2 + (i>>1)].h[i&1]
                                : (float)dP[0][(ct-4)*2 + (i>>1)].h[i&1];
            float f1 = (ct < 4) ? (float)sP[1][ct*2 + (i>>1)].h[i&1]
                                : (float)dP[1][(ct-4)*2 + (i>>1)].h[i&1];
            tgt[(0*16 + quad*4+i)*PS + col] = (_Float16)(alpha*acc0[i] + (1.f-alpha)*f0);
            tgt[(1*16 + quad*4+i)*PS + col] = (_Float16)(alpha*acc1[i] + (1.f-alpha)*f1);
        }
    }
    wait_lds();
    // ---- mlp2: 128->64 relu (reads Fs|Fd, writes Fs), 64->64 relu, dot ----
    read_a128(Fs, Fd, a, m, quad);
    mm2<4, true>(a, W8 + 7168, Fs, m, quad, lane); wait_lds();
    read_a<2>(Fs, a, m, quad);
    float rsum0[4] = {0.f,0.f,0.f,0.f}, rsum1[4] = {0.f,0.f,0.f,0.f};
#pragma unroll
    for (int ct = 0; ct < 4; ct++) {
        f32x4 acc0 = {0.f,0.f,0.f,0.f}, acc1 = {0.f,0.f,0.f,0.f};
#pragma unroll
        for (int kc = 0; kc < 2; kc++) {
            f16x8 b = W8[8192 + (ct*2+kc)*64 + lane];
            acc0 = __builtin_amdgcn_mfma_f32_16x16x32_f16(a[0][kc], b, acc0, 0, 0, 0);
            acc1 = __builtin_amdgcn_mfma_f32_16x16x32_f16(a[1][kc], b, acc1, 0, 0, 0);
        }
        float wv = w2out[ct*16 + m];
#pragma unroll
        for (int i = 0; i < 4; i++) {
            rsum0[i] += fmaxf(acc0[i], 0.f) * wv;
            rsum1[i] += fmaxf(acc1[i], 0.f) * wv;
        }
    }
#pragma unroll
    for (int off = 1; off < 16; off <<= 1) {
#pragma unroll
        for (int i = 0; i < 4; i++) {
            rsum0[i] += __shfl_xor(rsum0[i], off, 64);
            rsum1[i] += __shfl_xor(rsum1[i], off, 64);
        }
    }
    if (m == 0) {
#pragma unroll
        for (int i = 0; i < 4; i++) {
            out[pbase + 0*16 + quad*4 + i] = rsum0[i];
            out[pbase + 1*16 + quad*4 + i] = rsum1[i];
        }
    }
}

// ---------------------------------------------------------------------------
extern "C" void kernel_launch(void* const* d_in, const int* in_sizes, int n_in,
                              void* d_out, int out_size, void* d_ws, size_t ws_size,
                              hipStream_t stream) {
    const float* x      = (const float*)d_in[0];
    const float* t      = (const float*)d_in[1];
    const float* alpha  = (const float*)d_in[2];
    const float* tab_s  = (const float*)d_in[3];
    const float* ws_in  = (const float*)d_in[4];
    const float* ws_hid = (const float*)d_in[5];
    const float* ws_out = (const float*)d_in[6];
    const float* tab_d  = (const float*)d_in[7];
    const float* wd_in  = (const float*)d_in[8];
    const float* wd_hid = (const float*)d_in[9];
    const float* wd_out = (const float*)d_in[10];
    const float* w1_in  = (const float*)d_in[11];
    const float* w1_hid = (const float*)d_in[12];
    const float* w1_out = (const float*)d_in[13];
    const float* w2_in  = (const float*)d_in[14];
    const float* w2_hid = (const float*)d_in[15];
    const float* w2_out = (const float*)d_in[16];
    float* out = (float*)d_out;

    char* ws = (char*)d_ws;
    _Float16* Wfrag = (_Float16*)ws;                       // 139264 B
    uint2*    Tc    = (uint2*)(ws + 139264);               // 64 MiB combined table
    uint32_t* EncS  = (uint32_t*)(ws + 139264 + 67108864); // 32 MiB [lvl][pt]
    uint32_t* EncD  = EncS + (size_t)LVLS * NPTS;          // 32 MiB [lvl][pt]
    size_t needed = 139264 + 67108864 + 2ull * 33554432ull;
    if (ws_size < needed) return;

    WPtrs wp;
    wp.p[0] = ws_in;  wp.p[1] = ws_hid; wp.p[2] = ws_out;
    wp.p[3] = wd_in;  wp.p[4] = wd_hid; wp.p[5] = wd_out;
    wp.p[6] = w1_in;  wp.p[7] = w1_hid; wp.p[8] = w1_out;
    wp.p[9] = w2_in;  wp.p[10] = w2_hid;

    k_build  <<<41232, 256, 0, stream>>>(tab_s, tab_d, t, Tc, wp, Wfrag);
    k_encode <<<2048,  256, 0, stream>>>(x, Tc, EncS, EncD);
    k_mlp    <<<NPTS/128, 256, 0, stream>>>(EncS, EncD, Wfrag, alpha, w2_out, out);
}

// Round 2
// 548.442 us; speedup vs baseline: 1.1062x; 1.1062x over previous
//
#include <hip/hip_runtime.h>
#include <hip/hip_bf16.h>
#include <stdint.h>

#define LVLS 16
#define TSZ  524288          // hash table size per level (2^19)
#define TMASK 0x7FFFFu
#define NPTS 524288
#define P1 2654435761u
#define P2 805459861u
#define P3 3674653429u

// floor(16 * 1.5^l), hardcoded
__constant__ float RES_TAB[16] = {
    16.f, 24.f, 36.f, 54.f, 81.f, 121.f, 182.f, 273.f,
    410.f, 615.f, 922.f, 1383.f, 2075.f, 3113.f, 4670.f, 7006.f};

using f16x8 = __attribute__((ext_vector_type(8))) _Float16;
using f32x4 = __attribute__((ext_vector_type(4))) float;
using u32x8 = __attribute__((ext_vector_type(8))) uint32_t;

union PackF16 { uint32_t u; _Float16 h[2]; };

constexpr int PS = 72;    // LDS row pitch (64 cols + 8 pad)

struct WPtrs { const float* p[11]; };

// ---------------------------------------------------------------------------
// Kernel B: XCD-pinned table build + weight swizzle (merged). Unchanged.
// ---------------------------------------------------------------------------
__global__ void k_build(const float* __restrict__ ts, const float* __restrict__ td,
                        const float* __restrict__ tptr, uint2* __restrict__ Tc,
                        WPtrs wp, _Float16* __restrict__ wdst) {
    int B = blockIdx.x;
    int tid = threadIdx.x;
    if (B < 40960) {
        int c = B & 7, j = B >> 3;
        int l, i;
        if (j < 1024) {
            l = c >> 1;
            i = (c & 1) * 262144 + j * 256 + tid;
        } else if (j < 3072) {
            l = 12 + (c >> 1);
            i = (j - 1024) * 256 + tid;
        } else {
            l = 4 + c;
            i = (j - 3072) * 256 + tid;
        }
        int id = l * TSZ + i;
        float2 sv = ((const float2*)ts)[id];
        float res = RES_TAB[l];
        float tv  = tptr[0];
        float pt  = tv * res;
        float fpt = floorf(pt);
        float ft  = pt - fpt;
        uint32_t ut = (uint32_t)(int)fpt;
        uint32_t h0 = (ut * P3) & TMASK;
        uint32_t h1 = ((ut + 1u) * P3) & TMASK;
        const float2* tdl = (const float2*)td + (size_t)l * TSZ;
        float2 a = tdl[i ^ h0];
        float2 b = tdl[i ^ h1];
        PackF16 o0, o1;
        o0.h[0] = (_Float16)sv.x; o0.h[1] = (_Float16)sv.y;
        o1.h[0] = (_Float16)((1.f - ft) * a.x + ft * b.x);
        o1.h[1] = (_Float16)((1.f - ft) * a.y + ft * b.y);
        Tc[id] = make_uint2(o0.u, o1.u);
    } else {
        int id = (B - 40960) * 256 + tid;
        if (id >= 69632) return;
        const int OFF[16] = {0,2048,6144,10240,14336,18432,20480,24576,28672,
                             32768,36864,45056,49152,57344,65536,69632};
        const int KK[15]  = {32,64,64,64,64,32,64,64,64,64,128,64,64,128,64};
        const int NN[15]  = {64,64,64,64,64,64,64,64,64,64,64,64,128,64,64};
        const int PSEL[15]= {0,1,1,1,2,3,4,4,4,5,6,7,8,9,10};
        const int POFF[15]= {0,0,4096,8192,0,0,0,4096,8192,0,0,0,0,0,0};
        int m = 0;
        while (id >= OFF[m+1]) m++;
        int local = id - OFF[m];
        int jj   = local & 7;
        int lane = (local >> 3) & 63;
        int blk  = local >> 9;
        int KC   = KK[m] >> 5;
        int ct   = blk / KC;
        int kc   = blk - ct * KC;
        int k    = kc*32 + ((lane>>4)<<3) + jj;
        int n    = ct*16 + (lane & 15);
        const float* src = wp.p[PSEL[m]] + POFF[m];
        wdst[id] = (_Float16)src[k * NN[m] + n];
    }
}

// ---------------------------------------------------------------------------
// Kernel E: hash-grid encode, XCD-sharded (unchanged schedule). Q=4 point
// batch with a REGISTER-PINNING FENCE: the 32 gather results are collected
// into 8 x u32x8 ext-vectors and an empty `asm volatile` with "+v" on all 8
// vectors sits between the gather loop and the accumulate loop. The asm
// reads every load result, so all 32 global_load_dwordx2 must issue before
// it (one vmcnt drain instead of 16); consumers depend on the asm outputs.
// Round-1 failure mode (compiler re-sank the loads, VGPR stayed 32) is
// structurally impossible here. Verification signal: VGPR ~96-112.
// ---------------------------------------------------------------------------
template<int Q>
__device__ __forceinline__ void enc_batch(const float* __restrict__ x,
                                          const uint2* __restrict__ tcl, float res,
                                          uint32_t* __restrict__ es,
                                          uint32_t* __restrict__ ed,
                                          int p0, int stride) {
    static_assert(Q == 4, "pin fence written for Q=4");
    u32x8 v8[Q*2];
    float wx[Q], wy[Q], wz[Q];
#pragma unroll
    for (int q = 0; q < Q; q++) {
        int p = p0 + q * stride;
        float px = x[p*3+0]*res, py = x[p*3+1]*res, pz = x[p*3+2]*res;
        float fx = floorf(px), fy = floorf(py), fz = floorf(pz);
        wx[q] = px-fx; wy[q] = py-fy; wz[q] = pz-fz;
        uint32_t ux = (uint32_t)(int)fx, uy = (uint32_t)(int)fy, uz = (uint32_t)(int)fz;
        uint32_t hx[2] = {ux, ux + 1u};
        uint32_t hy[2] = {uy * P1, (uy + 1u) * P1};
        uint32_t hz[2] = {uz * P2, (uz + 1u) * P2};
#pragma unroll
        for (int c = 0; c < 8; c++) {
            uint32_t idx = (hx[c&1] ^ hy[(c>>1)&1] ^ hz[c>>2]) & TMASK;
            uint2 t = tcl[idx];
            v8[q*2 + (c>>2)][(c&3)*2 + 0] = t.x;
            v8[q*2 + (c>>2)][(c&3)*2 + 1] = t.y;
        }
    }
    // Scheduling fence: forces all 32 loads to be issued (and live) here.
    asm volatile("" : "+v"(v8[0]), "+v"(v8[1]), "+v"(v8[2]), "+v"(v8[3]),
                      "+v"(v8[4]), "+v"(v8[5]), "+v"(v8[6]), "+v"(v8[7]));
#pragma unroll
    for (int q = 0; q < Q; q++) {
        float wxa[2] = {1.f-wx[q], wx[q]};
        float wya[2] = {1.f-wy[q], wy[q]};
        float wza[2] = {1.f-wz[q], wz[q]};
        float sA0 = 0.f, sA1 = 0.f, sD0 = 0.f, sD1 = 0.f;
#pragma unroll
        for (int c = 0; c < 8; c++) {
            float w = wxa[c&1] * wya[(c>>1)&1] * wza[c>>2];
            PackF16 s, d;
            s.u = v8[q*2 + (c>>2)][(c&3)*2 + 0];
            d.u = v8[q*2 + (c>>2)][(c&3)*2 + 1];
            sA0 += w * (float)s.h[0]; sA1 += w * (float)s.h[1];
            sD0 += w * (float)d.h[0]; sD1 += w * (float)d.h[1];
        }
        int p = p0 + q * stride;
        PackF16 o;
        o.h[0] = (_Float16)sA0; o.h[1] = (_Float16)sA1; es[p] = o.u;
        o.h[0] = (_Float16)sD0; o.h[1] = (_Float16)sD1; ed[p] = o.u;
    }
}

__launch_bounds__(256, 4)
__global__ void k_encode(const float* __restrict__ x,
                         const uint2* __restrict__ Tc,
                         uint32_t* __restrict__ EncS, uint32_t* __restrict__ EncD) {
    int tid = threadIdx.x;
    int c   = blockIdx.x & 7;
    int gt  = (blockIdx.x >> 3) * 256 + tid;   // 0..65535 within class
    // pass 0: exclusive hard level (hot from k_build) — 8 points, 2 batches
    {
        int l = 4 + c;
        const uint2* tcl = Tc + (size_t)l * TSZ;
        uint32_t* es = EncS + (size_t)l * NPTS;
        uint32_t* ed = EncD + (size_t)l * NPTS;
        float res = RES_TAB[l];
        enc_batch<4>(x, tcl, res, es, ed, gt,             65536);
        enc_batch<4>(x, tcl, res, es, ed, gt + 4 * 65536, 65536);
    }
    // pass 1: shared hard level, half point-set — 4 points, 1 batch
    {
        int l = 12 + (c >> 1);
        const uint2* tcl = Tc + (size_t)l * TSZ;
        uint32_t* es = EncS + (size_t)l * NPTS;
        uint32_t* ed = EncD + (size_t)l * NPTS;
        float res = RES_TAB[l];
        int pb = (c & 1) * 262144 + gt;
        enc_batch<4>(x, tcl, res, es, ed, pb, 65536);
    }
    // pass 2: coarse level, half point-set — 4 points, 1 batch
    {
        int l = c >> 1;
        const uint2* tcl = Tc + (size_t)l * TSZ;
        uint32_t* es = EncS + (size_t)l * NPTS;
        uint32_t* ed = EncD + (size_t)l * NPTS;
        float res = RES_TAB[l];
        int pb = (c & 1) * 262144 + gt;
        enc_batch<4>(x, tcl, res, es, ed, pb, 65536);
    }
}

// ---------------------------------------------------------------------------
// Kernel M: barrier-free MLP (r5/r6-verified, unchanged).
// ---------------------------------------------------------------------------
__device__ __forceinline__ void wait_lds() {
    asm volatile("s_waitcnt lgkmcnt(0)" ::: "memory");
}

template<int KC, bool RELU>
__device__ __forceinline__ void mm2(const f16x8 a[2][4], const f16x8* __restrict__ B,
                                    _Float16* dst, int m, int quad, int lane) {
#pragma unroll
    for (int ct = 0; ct < 4; ct++) {
        f32x4 acc0 = {0.f,0.f,0.f,0.f}, acc1 = {0.f,0.f,0.f,0.f};
#pragma unroll
        for (int kc = 0; kc < KC; kc++) {
            f16x8 b = B[(ct*KC+kc)*64 + lane];
            acc0 = __builtin_amdgcn_mfma_f32_16x16x32_f16(a[0][kc], b, acc0, 0, 0, 0);
            acc1 = __builtin_amdgcn_mfma_f32_16x16x32_f16(a[1][kc], b, acc1, 0, 0, 0);
        }
#pragma unroll
        for (int i = 0; i < 4; i++) {
            float v0 = acc0[i], v1 = acc1[i];
            if (RELU) { v0 = fmaxf(v0, 0.f); v1 = fmaxf(v1, 0.f); }
            dst[(0*16 + quad*4+i)*PS + ct*16 + m] = (_Float16)v0;
            dst[(1*16 + quad*4+i)*PS + ct*16 + m] = (_Float16)v1;
        }
    }
}

template<int KC>
__device__ __forceinline__ void mm2_keep(const f16x8 a[2][4], const f16x8* __restrict__ B,
                                         _Float16* dst, PackF16 P[2][8],
                                         int m, int quad, int lane) {
#pragma unroll
    for (int ct = 0; ct < 4; ct++) {
        f32x4 acc0 = {0.f,0.f,0.f,0.f}, acc1 = {0.f,0.f,0.f,0.f};
#pragma unroll
        for (int kc = 0; kc < KC; kc++) {
            f16x8 b = B[(ct*KC+kc)*64 + lane];
            acc0 = __builtin_amdgcn_mfma_f32_16x16x32_f16(a[0][kc], b, acc0, 0, 0, 0);
            acc1 = __builtin_amdgcn_mfma_f32_16x16x32_f16(a[1][kc], b, acc1, 0, 0, 0);
        }
#pragma unroll
        for (int ih = 0; ih < 2; ih++) {
            PackF16 p0, p1;
            p0.h[0] = (_Float16)acc0[ih*2+0]; p0.h[1] = (_Float16)acc0[ih*2+1];
            p1.h[0] = (_Float16)acc1[ih*2+0]; p1.h[1] = (_Float16)acc1[ih*2+1];
            P[0][ct*2+ih] = p0; P[1][ct*2+ih] = p1;
            dst[(0*16 + quad*4+ih*2+0)*PS + ct*16 + m] = p0.h[0];
            dst[(0*16 + quad*4+ih*2+1)*PS + ct*16 + m] = p0.h[1];
            dst[(1*16 + quad*4+ih*2+0)*PS + ct*16 + m] = p1.h[0];
            dst[(1*16 + quad*4+ih*2+1)*PS + ct*16 + m] = p1.h[1];
        }
    }
}

template<int KC>
__device__ __forceinline__ void read_a(const _Float16* buf, f16x8 a[2][4], int m, int quad) {
#pragma unroll
    for (int rt = 0; rt < 2; rt++)
#pragma unroll
        for (int kc = 0; kc < KC; kc++)
            a[rt][kc] = *(const f16x8*)(buf + (rt*16 + m)*PS + kc*32 + quad*8);
}

__device__ __forceinline__ void read_a128(const _Float16* Fs, const _Float16* Fd,
                                          f16x8 a[2][4], int m, int quad) {
#pragma unroll
    for (int rt = 0; rt < 2; rt++) {
#pragma unroll
        for (int kc = 0; kc < 2; kc++) {
            a[rt][kc]   = *(const f16x8*)(Fs + (rt*16 + m)*PS + kc*32 + quad*8);
            a[rt][kc+2] = *(const f16x8*)(Fd + (rt*16 + m)*PS + kc*32 + quad*8);
        }
    }
}

__device__ __forceinline__ void load_enc(const uint32_t* __restrict__ Enc,
                                         int pbase, int m, int quad, f16x8 a[2][4]) {
#pragma unroll
    for (int rt = 0; rt < 2; rt++) {
        union { uint32_t u[4]; f16x8 v; } cv;
        int p = pbase + rt*16 + m;
#pragma unroll
        for (int j = 0; j < 4; j++)
            cv.u[j] = Enc[(size_t)(quad*4 + j) * NPTS + p];
        a[rt][0] = cv.v;
    }
}

__launch_bounds__(256, 4)
__global__ void k_mlp(const uint32_t* __restrict__ EncS, const uint32_t* __restrict__ EncD,
                      const _Float16* __restrict__ Wfrag, const float* __restrict__ alphap,
                      const float* __restrict__ w2out, float* __restrict__ out) {
    __shared__ _Float16 FsB[4][32*PS];
    __shared__ _Float16 FdB[4][32*PS];
    int tid  = threadIdx.x;
    int wave = tid >> 6, lane = tid & 63;
    int m = lane & 15, quad = lane >> 4;
    int pbase = blockIdx.x * 128 + wave * 32;
    _Float16* Fs = FsB[wave];
    _Float16* Fd = FdB[wave];
    const f16x8* W8 = (const f16x8*)Wfrag;
    float alpha = alphap[0];

    f16x8 a[2][4];
    PackF16 sP[2][8], dP[2][8];

    // ---- static encoder chain, in-place in Fs ----
    load_enc(EncS, pbase, m, quad, a);
    mm2<1, true>(a, W8 + 0,    Fs, m, quad, lane); wait_lds();
    read_a<2>(Fs, a, m, quad);
    mm2<2, true>(a, W8 + 256,  Fs, m, quad, lane); wait_lds();
    read_a<2>(Fs, a, m, quad);
    mm2<2, true>(a, W8 + 768,  Fs, m, quad, lane); wait_lds();
    read_a<2>(Fs, a, m, quad);
    mm2<2, true>(a, W8 + 1280, Fs, m, quad, lane); wait_lds();
    read_a<2>(Fs, a, m, quad);
    mm2_keep<2>(a, W8 + 1792, Fs, sP, m, quad, lane);
    // ---- dynamic encoder chain, in-place in Fd ----
    load_enc(EncD, pbase, m, quad, a);
    mm2<1, true>(a, W8 + 2304, Fd, m, quad, lane); wait_lds();
    read_a<2>(Fd, a, m, quad);
    mm2<2, true>(a, W8 + 2560, Fd, m, quad, lane); wait_lds();
    read_a<2>(Fd, a, m, quad);
    mm2<2, true>(a, W8 + 3072, Fd, m, quad, lane); wait_lds();
    read_a<2>(Fd, a, m, quad);
    mm2<2, true>(a, W8 + 3584, Fd, m, quad, lane); wait_lds();
    read_a<2>(Fd, a, m, quad);
    mm2_keep<2>(a, W8 + 4096, Fd, dP, m, quad, lane); wait_lds();
    // ---- mlp1: 128->64 relu (reads Fs|Fd, writes Fs), 64->64 relu ----
    read_a128(Fs, Fd, a, m, quad);
    mm2<4, true>(a, W8 + 4608, Fs, m, quad, lane); wait_lds();
    read_a<2>(Fs, a, m, quad);
    mm2<2, true>(a, W8 + 5632, Fs, m, quad, lane); wait_lds();
    read_a<2>(Fs, a, m, quad);
    // ---- out1 (64->128) fused with skip blend -> Fs (cols 0..63) | Fd ----
#pragma unroll
    for (int ct = 0; ct < 8; ct++) {
        f32x4 acc0 = {0.f,0.f,0.f,0.f}, acc1 = {0.f,0.f,0.f,0.f};
#pragma unroll
        for (int kc = 0; kc < 2; kc++) {
            f16x8 b = W8[6144 + (ct*2+kc)*64 + lane];
            acc0 = __builtin_amdgcn_mfma_f32_16x16x32_f16(a[0][kc], b, acc0, 0, 0, 0);
            acc1 = __builtin_amdgcn_mfma_f32_16x16x32_f16(a[1][kc], b, acc1, 0, 0, 0);
        }
        _Float16* tgt = (ct < 4) ? Fs : Fd;
        int col = (ct & 3) * 16 + m;
#pragma unroll
        for (int i = 0; i < 4; i++) {
            float f0 = (ct < 4) ? (float)sP[0][ct*2 + (i>>1)].h[i&1]
                                : (float)dP[0][(ct-4)*2 + (i>>1)].h[i&1];
            float f1 = (ct < 4) ? (float)sP[1][ct*2 + (i>>1)].h[i&1]
                                : (float)dP[1][(ct-4)*2 + (i>>1)].h[i&1];
            tgt[(0*16 + quad*4+i)*PS + col] = (_Float16)(alpha*acc0[i] + (1.f-alpha)*f0);
            tgt[(1*16 + quad*4+i)*PS + col] = (_Float16)(alpha*acc1[i] + (1.f-alpha)*f1);
        }
    }
    wait_lds();
    // ---- mlp2: 128->64 relu (reads Fs|Fd, writes Fs), 64->64 relu, dot ----
    read_a128(Fs, Fd, a, m, quad);
    mm2<4, true>(a, W8 + 7168, Fs, m, quad, lane); wait_lds();
    read_a<2>(Fs, a, m, quad);
    float rsum0[4] = {0.f,0.f,0.f,0.f}, rsum1[4] = {0.f,0.f,0.f,0.f};
#pragma unroll
    for (int ct = 0; ct < 4; ct++) {
        f32x4 acc0 = {0.f,0.f,0.f,0.f}, acc1 = {0.f,0.f,0.f,0.f};
#pragma unroll
        for (int kc = 0; kc < 2; kc++) {
            f16x8 b = W8[8192 + (ct*2+kc)*64 + lane];
            acc0 = __builtin_amdgcn_mfma_f32_16x16x32_f16(a[0][kc], b, acc0, 0, 0, 0);
            acc1 = __builtin_amdgcn_mfma_f32_16x16x32_f16(a[1][kc], b, acc1, 0, 0, 0);
        }
        float wv = w2out[ct*16 + m];
#pragma unroll
        for (int i = 0; i < 4; i++) {
            rsum0[i] += fmaxf(acc0[i], 0.f) * wv;
            rsum1[i] += fmaxf(acc1[i], 0.f) * wv;
        }
    }
#pragma unroll
    for (int off = 1; off < 16; off <<= 1) {
#pragma unroll
        for (int i = 0; i < 4; i++) {
            rsum0[i] += __shfl_xor(rsum0[i], off, 64);
            rsum1[i] += __shfl_xor(rsum1[i], off, 64);
        }
    }
    if (m == 0) {
#pragma unroll
        for (int i = 0; i < 4; i++) {
            out[pbase + 0*16 + quad*4 + i] = rsum0[i];
            out[pbase + 1*16 + quad*4 + i] = rsum1[i];
        }
    }
}

// ---------------------------------------------------------------------------
extern "C" void kernel_launch(void* const* d_in, const int* in_sizes, int n_in,
                              void* d_out, int out_size, void* d_ws, size_t ws_size,
                              hipStream_t stream) {
    const float* x      = (const float*)d_in[0];
    const float* t      = (const float*)d_in[1];
    const float* alpha  = (const float*)d_in[2];
    const float* tab_s  = (const float*)d_in[3];
    const float* ws_in  = (const float*)d_in[4];
    const float* ws_hid = (const float*)d_in[5];
    const float* ws_out = (const float*)d_in[6];
    const float* tab_d  = (const float*)d_in[7];
    const float* wd_in  = (const float*)d_in[8];
    const float* wd_hid = (const float*)d_in[9];
    const float* wd_out = (const float*)d_in[10];
    const float* w1_in  = (const float*)d_in[11];
    const float* w1_hid = (const float*)d_in[12];
    const float* w1_out = (const float*)d_in[13];
    const float* w2_in  = (const float*)d_in[14];
    const float* w2_hid = (const float*)d_in[15];
    const float* w2_out = (const float*)d_in[16];
    float* out = (float*)d_out;

    char* ws = (char*)d_ws;
    _Float16* Wfrag = (_Float16*)ws;                       // 139264 B
    uint2*    Tc    = (uint2*)(ws + 139264);               // 64 MiB combined table
    uint32_t* EncS  = (uint32_t*)(ws + 139264 + 67108864); // 32 MiB [lvl][pt]
    uint32_t* EncD  = EncS + (size_t)LVLS * NPTS;          // 32 MiB [lvl][pt]
    size_t needed = 139264 + 67108864 + 2ull * 33554432ull;
    if (ws_size < needed) return;

    WPtrs wp;
    wp.p[0] = ws_in;  wp.p[1] = ws_hid; wp.p[2] = ws_out;
    wp.p[3] = wd_in;  wp.p[4] = wd_hid; wp.p[5] = wd_out;
    wp.p[6] = w1_in;  wp.p[7] = w1_hid; wp.p[8] = w1_out;
    wp.p[9] = w2_in;  wp.p[10] = w2_hid;

    k_build  <<<41232, 256, 0, stream>>>(tab_s, tab_d, t, Tc, wp, Wfrag);
    k_encode <<<2048,  256, 0, stream>>>(x, Tc, EncS, EncD);
    k_mlp    <<<NPTS/128, 256, 0, stream>>>(EncS, EncD, Wfrag, alpha, w2_out, out);
}